// Round 4
// baseline (98.018 us; speedup 1.0000x reference)
//
#include <hip/hip_runtime.h>

// SE block: gap = mean(relation, spatial); bottle = relu(gap@W1^T + b1);
// gate = sigmoid(bottle@W2^T + b2); scale = float(int64(gate)); out = relation*scale.
// Shapes: relation [B=64, HEADS=16, 256, 256] fp32; W1 [4,16]; b1 [4]; W2 [16,4]; b2 [16].
//
// Traffic floor: read 268 MB (GAP) + write 268 MB (output) = 536 MB ~ 80 us.
// scale is float(int64(sigmoid(x))) -> exactly 0.0 or 1.0; when 0 the multiply
// kernel skips reading `relation` entirely (write-only zeros).

#define NB 64
#define NHEADS 16
#define NPLANES (NB * NHEADS)       // 1024 planes
#define HW 65536                    // elements per plane
#define HW4 16384                   // float4s per plane
#define GAP_CHUNKS 4                // partial sums per plane
#define GAP_CHUNK4 (HW4 / GAP_CHUNKS)   // 4096 float4s per gap block
#define MUL_CHUNKS 4                // blocks per plane in multiply kernel
#define MUL_CHUNK4 (HW4 / MUL_CHUNKS)   // 4096 float4s per mul block

typedef float f32x4 __attribute__((ext_vector_type(4)));  // native vector for nontemporal builtins

// ------------- Kernel 1: quarter-plane partial sums (4096 blocks x 256 thr) -------------
__global__ __launch_bounds__(256) void se_gap_kernel(const float* __restrict__ rel,
                                                     float* __restrict__ partial) {
    const int blk = blockIdx.x;                     // = p*GAP_CHUNKS + q
    const f32x4* __restrict__ src = (const f32x4*)rel + (size_t)blk * GAP_CHUNK4;
    float s = 0.0f;
    #pragma unroll 8
    for (int i = threadIdx.x; i < GAP_CHUNK4; i += 256) {
        f32x4 v = __builtin_nontemporal_load(src + i);    // streaming read, no reuse
        s += (v.x + v.y) + (v.z + v.w);
    }
    // wave (64-lane) down reduce
    #pragma unroll
    for (int off = 32; off > 0; off >>= 1)
        s += __shfl_down(s, off, 64);
    __shared__ float ws[4];
    const int wave = threadIdx.x >> 6;
    if ((threadIdx.x & 63) == 0) ws[wave] = s;
    __syncthreads();
    if (threadIdx.x == 0)
        partial[blk] = (ws[0] + ws[1]) + (ws[2] + ws[3]);
}

// ------- Kernel 2: fused SE-MLP (block-uniform, scalarized) + broadcast multiply -------
__global__ __launch_bounds__(256) void se_mlp_mul_kernel(const float* __restrict__ rel,
                                                         const float* __restrict__ partial,
                                                         const float* __restrict__ W1,
                                                         const float* __restrict__ b1,
                                                         const float* __restrict__ W2,
                                                         const float* __restrict__ b2,
                                                         float* __restrict__ out) {
    const int p     = blockIdx.x >> 2;              // plane id = b*16 + h
    const int chunk = blockIdx.x & (MUL_CHUNKS - 1);
    const int b = p >> 4;
    const int h = p & (NHEADS - 1);

    // --- tiny SE MLP, all operands block-uniform -> scalar loads + uniform VALU ---
    float g[NHEADS];
    #pragma unroll
    for (int k = 0; k < NHEADS; ++k) {
        const float* pp = partial + (size_t)(b * NHEADS + k) * GAP_CHUNKS;
        g[k] = ((pp[0] + pp[1]) + (pp[2] + pp[3])) * (1.0f / (float)HW);
    }
    float bot[4];
    #pragma unroll
    for (int c = 0; c < 4; ++c) {
        float acc = b1[c];
        #pragma unroll
        for (int k = 0; k < NHEADS; ++k) acc += g[k] * W1[c * NHEADS + k];
        bot[c] = fmaxf(acc, 0.0f);
    }
    float acc = b2[h];
    #pragma unroll
    for (int c = 0; c < 4; ++c) acc += bot[c] * W2[h * 4 + c];
    const float gate = 1.0f / (1.0f + expf(-acc));            // sigmoid
    const float s = (float)(long long)gate;                   // astype(int64) trunc

    const size_t base4 = (size_t)p * HW4 + (size_t)chunk * MUL_CHUNK4;
    f32x4* __restrict__ dst = (f32x4*)out + base4;
    if (s == 0.0f) {
        // output exactly zero; skip reading relation entirely
        const f32x4 z = {0.0f, 0.0f, 0.0f, 0.0f};
        #pragma unroll 4
        for (int i = threadIdx.x; i < MUL_CHUNK4; i += 256)
            __builtin_nontemporal_store(z, dst + i);
    } else {
        const f32x4* __restrict__ src = (const f32x4*)rel + base4;
        #pragma unroll 4
        for (int i = threadIdx.x; i < MUL_CHUNK4; i += 256) {
            f32x4 v = __builtin_nontemporal_load(src + i);
            v *= s;
            __builtin_nontemporal_store(v, dst + i);
        }
    }
}

extern "C" void kernel_launch(void* const* d_in, const int* in_sizes, int n_in,
                              void* d_out, int out_size, void* d_ws, size_t ws_size,
                              hipStream_t stream) {
    const float* rel = (const float*)d_in[0];
    const float* W1  = (const float*)d_in[1];
    const float* b1  = (const float*)d_in[2];
    const float* W2  = (const float*)d_in[3];
    const float* b2  = (const float*)d_in[4];
    float* out = (float*)d_out;

    float* partial = (float*)d_ws;                // NPLANES * GAP_CHUNKS floats

    se_gap_kernel<<<NPLANES * GAP_CHUNKS, 256, 0, stream>>>(rel, partial);
    se_mlp_mul_kernel<<<NPLANES * MUL_CHUNKS, 256, 0, stream>>>(rel, partial, W1, b1, W2, b2, out);
}